// Round 8
// baseline (156.173 us; speedup 1.0000x reference)
//
#include <hip/hip_runtime.h>
#include <math.h>

typedef __attribute__((ext_vector_type(8))) short bf16x8;
typedef __attribute__((ext_vector_type(4))) float f32x4;

namespace {
constexpr int NN  = 12;
constexpr int FIN = 128;
constexpr int D1  = 256;
constexpr int C2  = 64;
constexpr float SLOPE = 0.2f;

__device__ __forceinline__ unsigned short f2bf(float f) {
    unsigned u = __builtin_bit_cast(unsigned, f);
    u += 0x7FFFu + ((u >> 16) & 1u);     // RNE
    return (unsigned short)(u >> 16);
}
// ELU via hardware v_exp_f32 (~1e-7 err, ~5x cheaper than libm expm1f).
__device__ __forceinline__ float elu1(float x) { return x > 0.f ? x : __expf(x) - 1.f; }
__device__ __forceinline__ float lrelu(float x) { return x > 0.f ? x : SLOPE * x; }
}

// ---------------------------------------------------------------------------
// Pack B-operands into bf16 MFMA fragment layout, e-tiles folded in (R3).
// ---------------------------------------------------------------------------
__global__ void prep_weights(const float* __restrict__ W1, const float* __restrict__ as1,
                             const float* __restrict__ ad1,
                             const float* __restrict__ W2, const float* __restrict__ as2,
                             const float* __restrict__ ad2,
                             unsigned short* __restrict__ wsB1, unsigned short* __restrict__ wsB2) {
    int t = blockIdx.x * 256 + threadIdx.x;
    if (t < 34816) {
        int i = t & 7, l = (t >> 3) & 63, kn = t >> 9;    // kn 0..67
        int kt = kn / 17, nt = kn % 17;
        int k = kt * 32 + (l >> 4) * 8 + i;
        float v = 0.f;
        if (nt < 16) {
            v = W1[k * 256 + nt * 16 + (l & 15)];
        } else {
            int cc = l & 15;
            if (cc < 4)      for (int c = 0; c < 64; ++c) v += W1[k * 256 + cc * 64 + c] * as1[cc * 64 + c];
            else if (cc < 8) for (int c = 0; c < 64; ++c) v += W1[k * 256 + (cc - 4) * 64 + c] * ad1[(cc - 4) * 64 + c];
        }
        wsB1[t] = f2bf(v);
    } else if (t < 55296) {
        int t2 = t - 34816;
        int i = t2 & 7, l = (t2 >> 3) & 63, kn = t2 >> 9; // kn 0..39
        int kt = kn / 5, nt = kn % 5;
        int k = kt * 32 + (l >> 4) * 8 + i;
        float v = 0.f;
        if (nt < 4) {
            v = W2[k * 64 + nt * 16 + (l & 15)];
        } else {
            int cc = l & 15;
            if (cc == 0)      for (int c = 0; c < 64; ++c) v += W2[k * 64 + c] * as2[c];
            else if (cc == 1) for (int c = 0; c < 64; ++c) v += W2[k * 64 + c] * ad2[c];
        }
        wsB2[t2] = f2bf(v);
    }
}

// ---------------------------------------------------------------------------
// Main fused kernel: 4 graphs (48 rows), 512 threads (8 waves) per block.
// Aggregations run TRANSPOSED (x2^T = h1^T @ alpha^T): D-fragments hold 4
// consecutive CHANNELS -> packed uint2 LDS stores instead of 24 scalar b16.
// ---------------------------------------------------------------------------
__global__ __launch_bounds__(512, 4) void gat_mfma7(
    const float* __restrict__ x_in,
    const unsigned short* __restrict__ wsB1,
    const unsigned short* __restrict__ wsB2,
    const float* __restrict__ b1, const float* __restrict__ b2,
    const float* __restrict__ Wc1, const float* __restrict__ bc1,
    const float* __restrict__ Wc2, const float* __restrict__ bc2,
    float* __restrict__ out)
{
    // R0: x bf16 [48][128] swz (12288)           | x3T f32 [64 o][50 i] rows 200B (12800)
    // R1: h1T bf16 [256 o][64 j] swz (32768)     | h2T [64 o][64 j] (8192) + alpha2 [48 i][64 j] @+8192 (6144)
    // R2: alpha1 bf16 [4 h][48 i][64 j] (24576)  | x2 bf16 [48 i][256 o] rows 512B swz (24576)
    __shared__ __align__(16) unsigned char R0[13056];
    __shared__ __align__(16) unsigned char R1[32768];
    __shared__ __align__(16) unsigned char R2[24576];
    __shared__ float eS1[48][4], eD1[48][4];
    __shared__ float eS2[48], eD2[48];
    __shared__ float gpool[4][64];

    const int b = blockIdx.x, t = threadIdx.x;
    const int w = t >> 6, l = t & 63, l15 = l & 15, lq = l >> 4;

    // ---- P0: stage x (f32 -> bf16 LDS swizzled) + zero-fill padding regions
    {
        const float4* xs = (const float4*)(x_in + (size_t)b * (4 * NN * FIN));
        #pragma unroll
        for (int it = 0; it < 3; ++it) {
            int q = t + 512 * it;                          // 1536 float4
            float4 v = xs[q];
            int e0 = q << 2, r = e0 >> 7, k = e0 & 127;
            int addr = ((r << 8) + (k << 1)) ^ ((r & 7) << 4);
            unsigned p0 = (unsigned)f2bf(v.x) | ((unsigned)f2bf(v.y) << 16);
            unsigned p1 = (unsigned)f2bf(v.z) | ((unsigned)f2bf(v.w) << 16);
            *(uint2*)(R0 + addr) = make_uint2(p0, p1);
        }
        #pragma unroll
        for (int it = 0; it < 3; ++it)                     // zero alpha1 (24576 B)
            *(uint4*)(R2 + ((it * 512 + t) << 4)) = make_uint4(0, 0, 0, 0);
        {                                                  // zero h1T rows j=48..63 (512 x 16B)
            int col = t >> 1, bs = 6 + (t & 1);
            int addr = ((col << 7) + (bs << 4)) ^ ((col & 7) << 4);
            *(uint4*)(R1 + addr) = make_uint4(0, 0, 0, 0);
        }
    }
    __syncthreads();

    // ---- P1: GEMM1 (x @ [W1 | va1]) -> h1T bf16 + eS1/eD1 direct
    //      wave pair (2h, 2h+1) splits head h's 4 n-tiles into 2+2
    {
        const uint4* pb = (const uint4*)wsB1;
        const int h = w >> 1, half = w & 1;
        bf16x8 Bf[2][4];
        #pragma unroll
        for (int ngl = 0; ngl < 2; ++ngl)
            #pragma unroll
            for (int kt = 0; kt < 4; ++kt)
                Bf[ngl][kt] = __builtin_bit_cast(bf16x8, pb[(kt * 17 + (h * 4 + half * 2 + ngl)) * 64 + l]);
        bf16x8 Bfe[4];
        if (w == 0) {
            #pragma unroll
            for (int kt = 0; kt < 4; ++kt)
                Bfe[kt] = __builtin_bit_cast(bf16x8, pb[(kt * 17 + 16) * 64 + l]);
        }
        #pragma unroll
        for (int m = 0; m < 3; ++m) {
            int r = m * 16 + l15, abase = (r << 8) + (lq << 4), swz = (r & 7) << 4;
            bf16x8 Af[4];
            #pragma unroll
            for (int kt = 0; kt < 4; ++kt)
                Af[kt] = *(const bf16x8*)(R0 + ((abase + (kt << 6)) ^ swz));
            f32x4 acc[2];
            #pragma unroll
            for (int ngl = 0; ngl < 2; ++ngl) acc[ngl] = (f32x4){0.f, 0.f, 0.f, 0.f};
            #pragma unroll
            for (int ngl = 0; ngl < 2; ++ngl)
                #pragma unroll
                for (int kt = 0; kt < 4; ++kt)
                    acc[ngl] = __builtin_amdgcn_mfma_f32_16x16x32_bf16(Af[kt], Bf[ngl][kt], acc[ngl], 0, 0, 0);
            int row0 = m * 16 + lq * 4;
            #pragma unroll
            for (int ngl = 0; ngl < 2; ++ngl) {            // packed b64 store (4 consecutive j-rows)
                int col = h * 64 + (half * 2 + ngl) * 16 + l15;
                unsigned q0 = (unsigned)f2bf(acc[ngl][0]) | ((unsigned)f2bf(acc[ngl][1]) << 16);
                unsigned q1 = (unsigned)f2bf(acc[ngl][2]) | ((unsigned)f2bf(acc[ngl][3]) << 16);
                int addr = ((col << 7) + (row0 << 1)) ^ ((col & 7) << 4);
                *(uint2*)(R1 + addr) = make_uint2(q0, q1);
            }
            if (w == 0) {
                f32x4 acce = (f32x4){0.f, 0.f, 0.f, 0.f};
                #pragma unroll
                for (int kt = 0; kt < 4; ++kt)
                    acce = __builtin_amdgcn_mfma_f32_16x16x32_bf16(Af[kt], Bfe[kt], acce, 0, 0, 0);
                if (l15 < 8) {
                    #pragma unroll
                    for (int reg = 0; reg < 4; ++reg) {
                        int row = row0 + reg;
                        if (l15 < 4) eS1[row][l15] = acce[reg];
                        else         eD1[row][l15 - 4] = acce[reg];
                    }
                }
            }
        }
    }
    __syncthreads();

    // ---- P2: softmax1 -> alpha1[h][i][j] bf16, packed uint2 writes
    if (t < 192) {
        int g = t / 48, rem = t % 48, i = rem >> 2, h = rem & 3;
        int rowi = g * 12 + i;
        float edi = eD1[rowi][h];
        float lv[12]; float mx = -1e30f;
        #pragma unroll
        for (int j = 0; j < 12; ++j) {
            float v = lrelu(edi + eS1[g * 12 + j][h]);
            lv[j] = v; mx = fmaxf(mx, v);
        }
        float s = 0.f;
        #pragma unroll
        for (int j = 0; j < 12; ++j) { lv[j] = __expf(lv[j] - mx); s += lv[j]; }
        float inv = 1.f / s;
        unsigned char* base = R2 + h * 6144;
        int rb = rowi << 7, swz = (rowi & 7) << 4, ob = g * 24;
        #pragma unroll
        for (int p = 0; p < 3; ++p) {
            unsigned q0 = (unsigned)f2bf(lv[4*p]   * inv) | ((unsigned)f2bf(lv[4*p+1] * inv) << 16);
            unsigned q1 = (unsigned)f2bf(lv[4*p+2] * inv) | ((unsigned)f2bf(lv[4*p+3] * inv) << 16);
            int addr = (rb + ob + p * 8) ^ swz;
            *(uint2*)(base + addr) = make_uint2(q0, q1);
        }
    }
    __syncthreads();

    // ---- P3: aggregation1 TRANSPOSED: x2T[o][i] = sum_j h1T[o][j] * alpha[i][j]
    //      A = h1T (R1), B = alpha^T (from row-major alpha rows), D-> packed stores.
    {
        const int h = w >> 1, half = w & 1;
        bf16x8 Ba[3][2];
        const unsigned char* ab = R2 + h * 6144;
        #pragma unroll
        for (int nt = 0; nt < 3; ++nt)
            #pragma unroll
            for (int kt = 0; kt < 2; ++kt) {
                int i = nt * 16 + l15;
                Ba[nt][kt] = *(const bf16x8*)(ab + (((i << 7) + (kt << 6) + (lq << 4)) ^ ((i & 7) << 4)));
            }
        __syncthreads();                                   // all alpha read before x2 overwrites R2
        #pragma unroll
        for (int mtl = 0; mtl < 2; ++mtl) {
            int mt = half * 2 + mtl;
            int o = h * 64 + mt * 16 + l15;
            bf16x8 Ah[2];
            #pragma unroll
            for (int kt = 0; kt < 2; ++kt)
                Ah[kt] = *(const bf16x8*)(R1 + (((o << 7) + (kt << 6) + (lq << 4)) ^ ((o & 7) << 4)));
            int o0 = h * 64 + mt * 16 + (lq << 2);
            float4 b1v = *(const float4*)(b1 + o0);
            float bb[4] = {b1v.x, b1v.y, b1v.z, b1v.w};
            #pragma unroll
            for (int nt = 0; nt < 3; ++nt) {
                f32x4 acc = (f32x4){0.f, 0.f, 0.f, 0.f};
                #pragma unroll
                for (int kt = 0; kt < 2; ++kt)
                    acc = __builtin_amdgcn_mfma_f32_16x16x32_bf16(Ah[kt], Ba[nt][kt], acc, 0, 0, 0);
                float e0 = elu1(acc[0] + bb[0]), e1 = elu1(acc[1] + bb[1]);
                float e2 = elu1(acc[2] + bb[2]), e3 = elu1(acc[3] + bb[3]);
                int i = nt * 16 + l15;
                unsigned q0 = (unsigned)f2bf(e0) | ((unsigned)f2bf(e1) << 16);
                unsigned q1 = (unsigned)f2bf(e2) | ((unsigned)f2bf(e3) << 16);
                int addr = ((i << 9) + (o0 << 1)) ^ ((i & 7) << 4);
                *(uint2*)(R2 + addr) = make_uint2(q0, q1);
            }
        }
    }
    __syncthreads();

    // ---- P4: GEMM2 (x2 @ [W2 | va2]) -> h2T bf16 + eS2/eD2; zero pads
    //      x2 now [i][256 o] rows 512B; 15 (tile,m) units over 8 waves
    {
        if (t < 128) {                                     // zero h2T rows j=48..63
            int col = t >> 1, bs = 6 + (t & 1);
            int addr = ((col << 7) + (bs << 4)) ^ ((col & 7) << 4);
            *(uint4*)(R1 + addr) = make_uint4(0, 0, 0, 0);
        }
        if (t < 192) {                                     // zero alpha2 (6144 B)
            *(uint4*)(R1 + 8192 + (t << 4)) = make_uint4(0, 0, 0, 0);
            *(uint4*)(R1 + 8192 + ((t + 192) << 4)) = make_uint4(0, 0, 0, 0);
        }
        const uint4* pb2 = (const uint4*)wsB2;
        #pragma unroll
        for (int ui = 0; ui < 2; ++ui) {
            int u = w * 2 + ui;
            if (u < 15) {
                int tile = u / 3, m = u % 3;
                bf16x8 Bg[8];
                #pragma unroll
                for (int kt = 0; kt < 8; ++kt)
                    Bg[kt] = __builtin_bit_cast(bf16x8, pb2[(kt * 5 + tile) * 64 + l]);
                int r = m * 16 + l15, swz = (r & 7) << 4;
                f32x4 acc = (f32x4){0.f, 0.f, 0.f, 0.f};
                #pragma unroll
                for (int kt = 0; kt < 8; ++kt) {
                    int addr = ((r << 9) + (kt << 6) + (lq << 4)) ^ swz;
                    bf16x8 Ax = *(const bf16x8*)(R2 + addr);
                    acc = __builtin_amdgcn_mfma_f32_16x16x32_bf16(Ax, Bg[kt], acc, 0, 0, 0);
                }
                int row0 = m * 16 + lq * 4;
                if (tile < 4) {
                    int col = tile * 16 + l15;
                    unsigned q0 = (unsigned)f2bf(acc[0]) | ((unsigned)f2bf(acc[1]) << 16);
                    unsigned q1 = (unsigned)f2bf(acc[2]) | ((unsigned)f2bf(acc[3]) << 16);
                    int addr = ((col << 7) + (row0 << 1)) ^ ((col & 7) << 4);
                    *(uint2*)(R1 + addr) = make_uint2(q0, q1);
                } else if (l15 < 2) {                      // e-tile
                    #pragma unroll
                    for (int reg = 0; reg < 4; ++reg) {
                        int row = row0 + reg;
                        if (l15 == 0) eS2[row] = acc[reg];
                        else          eD2[row] = acc[reg];
                    }
                }
            }
        }
    }
    __syncthreads();

    // ---- P5: softmax2 -> alpha2[i][j] bf16, packed uint2 writes
    if (t < 48) {
        int g = t / 12;
        float edi = eD2[t];
        float lv[12]; float mx = -1e30f;
        #pragma unroll
        for (int j = 0; j < 12; ++j) {
            float v = lrelu(edi + eS2[g * 12 + j]);
            lv[j] = v; mx = fmaxf(mx, v);
        }
        float s = 0.f;
        #pragma unroll
        for (int j = 0; j < 12; ++j) { lv[j] = __expf(lv[j] - mx); s += lv[j]; }
        float inv = 1.f / s;
        int rb = t << 7, swz = (t & 7) << 4, ob = g * 24;
        #pragma unroll
        for (int p = 0; p < 3; ++p) {
            unsigned q0 = (unsigned)f2bf(lv[4*p]   * inv) | ((unsigned)f2bf(lv[4*p+1] * inv) << 16);
            unsigned q1 = (unsigned)f2bf(lv[4*p+2] * inv) | ((unsigned)f2bf(lv[4*p+3] * inv) << 16);
            int addr = 8192 + ((rb + ob + p * 8) ^ swz);
            *(uint2*)(R1 + addr) = make_uint2(q0, q1);
        }
    }
    __syncthreads();

    // ---- P6: aggregation2 TRANSPOSED: x3T[o][i] -> R0 rows 200 B
    //      12 (mt, nt) units: waves 0..3 -> mt=w, nt {0,1}; waves 4..7 -> mt=w-4, nt=2
    {
        const int mt = w & 3;
        const int nt0 = (w < 4) ? 0 : 2;
        const int ntc = (w < 4) ? 2 : 1;
        int o = mt * 16 + l15;
        bf16x8 Ah2[2];
        #pragma unroll
        for (int kt = 0; kt < 2; ++kt)
            Ah2[kt] = *(const bf16x8*)(R1 + (((o << 7) + (kt << 6) + (lq << 4)) ^ ((o & 7) << 4)));
        int ost = mt * 16 + (lq << 2);
        float4 b2v = *(const float4*)(b2 + ost);
        float bb[4] = {b2v.x, b2v.y, b2v.z, b2v.w};
        for (int ni = 0; ni < ntc; ++ni) {
            int nt = nt0 + ni;
            int i = nt * 16 + l15;
            bf16x8 Ba2[2];
            #pragma unroll
            for (int kt = 0; kt < 2; ++kt)
                Ba2[kt] = *(const bf16x8*)(R1 + 8192 + (((i << 7) + (kt << 6) + (lq << 4)) ^ ((i & 7) << 4)));
            f32x4 acc = (f32x4){0.f, 0.f, 0.f, 0.f};
            #pragma unroll
            for (int kt = 0; kt < 2; ++kt)
                acc = __builtin_amdgcn_mfma_f32_16x16x32_bf16(Ah2[kt], Ba2[kt], acc, 0, 0, 0);
            #pragma unroll
            for (int reg = 0; reg < 4; ++reg)
                *(float*)(R0 + (ost + reg) * 200 + (i << 2)) = elu1(acc[reg] + bb[reg]);
        }
    }
    __syncthreads();

    // ---- pool: g[o] = mean over the graph's 12 nodes (contiguous in x3T row)
    if (t < 256) {
        int o = t & 63, g = t >> 6;
        const unsigned char* row = R0 + o * 200 + g * 48;
        float s = 0.f;
        #pragma unroll
        for (int p = 0; p < 6; ++p) {
            float2 v = *(const float2*)(row + p * 8);
            s += v.x + v.y;
        }
        gpool[g][o] = s * (1.0f / 12.0f);
    }
    __syncthreads();

    // ---- classifier 64 -> 32 (relu) -> 1
    if (t < 128) {
        int g = t >> 5, nr = t & 31;
        float acc = bc1[nr];
        #pragma unroll
        for (int cc = 0; cc < 64; ++cc)
            acc = fmaf(gpool[g][cc], Wc1[cc * 32 + nr], acc);
        float val = fmaxf(acc, 0.f) * Wc2[nr];
        #pragma unroll
        for (int msk = 1; msk < 32; msk <<= 1) val += __shfl_xor(val, msk);
        if (nr == 0) out[b * 4 + g] = val + bc2[0];
    }
}

// ---------------------------------------------------------------------------
// f32 fallback — used only if ws too small or B % 4 != 0
// ---------------------------------------------------------------------------
__global__ __launch_bounds__(256, 4) void gat_fused_f32(
    const float* __restrict__ x_in, const float* __restrict__ W1,
    const float* __restrict__ a_src1, const float* __restrict__ a_dst1,
    const float* __restrict__ b1, const float* __restrict__ W2,
    const float* __restrict__ a_src2, const float* __restrict__ a_dst2,
    const float* __restrict__ b2, const float* __restrict__ Wc1,
    const float* __restrict__ bc1, const float* __restrict__ Wc2,
    const float* __restrict__ bc2, float* __restrict__ out)
{
    __shared__ union {
        float x_l[NN][FIN];
        struct { float h2[NN][C2]; float x3[NN][C2]; } s2;
    } u;
    __shared__ float h1s[NN][D1];
    __shared__ float x2s[NN][D1];
    __shared__ float alpha1[NN][NN][4];
    __shared__ float e_s1[NN][4], e_d1[NN][4];
    __shared__ float e_s2[NN], e_d2[NN];
    __shared__ float alpha2[NN][NN];
    __shared__ float gph[C2];
    __shared__ float hdn[32];

    const int b = blockIdx.x, t = threadIdx.x;
    const float* xb = x_in + (size_t)b * (NN * FIN);
    for (int i = t; i < NN * FIN; i += 256) (&u.x_l[0][0])[i] = xb[i];
    __syncthreads();
    {
        const int o0 = (t & 127) * 2, n0 = (t >> 7) * 6;
        float acc[6][2];
        #pragma unroll
        for (int i = 0; i < 6; ++i) { acc[i][0] = 0.f; acc[i][1] = 0.f; }
        for (int f = 0; f < FIN; f += 4) {
            float4 xv[6];
            #pragma unroll
            for (int i = 0; i < 6; ++i) xv[i] = *(const float4*)&u.x_l[n0 + i][f];
            #pragma unroll
            for (int k = 0; k < 4; ++k) {
                const float2 wv = *(const float2*)&W1[(f + k) * D1 + o0];
                #pragma unroll
                for (int i = 0; i < 6; ++i) {
                    const float xs = ((const float*)&xv[i])[k];
                    acc[i][0] = fmaf(xs, wv.x, acc[i][0]);
                    acc[i][1] = fmaf(xs, wv.y, acc[i][1]);
                }
            }
        }
        #pragma unroll
        for (int i = 0; i < 6; ++i) { h1s[n0+i][o0] = acc[i][0]; h1s[n0+i][o0+1] = acc[i][1]; }
    }
    __syncthreads();
    if (t < NN * 4) {
        const int n = t >> 2, h = t & 3;
        float es = 0.f, ed = 0.f;
        for (int c = 0; c < 64; ++c) {
            const float v = h1s[n][h * 64 + c];
            es = fmaf(v, a_src1[h * 64 + c], es);
            ed = fmaf(v, a_dst1[h * 64 + c], ed);
        }
        e_s1[n][h] = es; e_d1[n][h] = ed;
    }
    __syncthreads();
    if (t < NN * 4) {
        const int i = t >> 2, h = t & 3;
        const float edi = e_d1[i][h];
        float lv[NN]; float m = -1e30f;
        #pragma unroll
        for (int j = 0; j < NN; ++j) {
            float v = edi + e_s1[j][h]; v = v > 0.f ? v : SLOPE * v;
            lv[j] = v; m = fmaxf(m, v);
        }
        float s = 0.f;
        #pragma unroll
        for (int j = 0; j < NN; ++j) { lv[j] = __expf(lv[j] - m); s += lv[j]; }
        const float inv = 1.f / s;
        #pragma unroll
        for (int j = 0; j < NN; ++j) alpha1[i][j][h] = lv[j] * inv;
    }
    __syncthreads();
    {
        const int o = t, h = o >> 6;
        const float bo = b1[o];
        float v[NN];
        #pragma unroll
        for (int j = 0; j < NN; ++j) v[j] = h1s[j][o];
        #pragma unroll
        for (int i = 0; i < NN; ++i) {
            float acc = 0.f;
            #pragma unroll
            for (int j = 0; j < NN; ++j) acc = fmaf(alpha1[i][j][h], v[j], acc);
            x2s[i][o] = acc + bo > 0.f ? acc + bo : expm1f(acc + bo);
        }
    }
    __syncthreads();
    {
        const int c = t & 63, n0 = (t >> 6) * 3;
        float acc[3] = {0.f, 0.f, 0.f};
        for (int f = 0; f < D1; f += 4) {
            float4 xv[3];
            #pragma unroll
            for (int i = 0; i < 3; ++i) xv[i] = *(const float4*)&x2s[n0 + i][f];
            #pragma unroll
            for (int k = 0; k < 4; ++k) {
                const float wv = W2[(f + k) * C2 + c];
                #pragma unroll
                for (int i = 0; i < 3; ++i) acc[i] = fmaf(((const float*)&xv[i])[k], wv, acc[i]);
            }
        }
        #pragma unroll
        for (int i = 0; i < 3; ++i) u.s2.h2[n0 + i][c] = acc[i];
    }
    __syncthreads();
    if (t < NN) {
        float es = 0.f, ed = 0.f;
        for (int c = 0; c < 64; c += 4) {
            const float4 v  = *(const float4*)&u.s2.h2[t][c];
            const float4 as = *(const float4*)&a_src2[c];
            const float4 ad = *(const float4*)&a_dst2[c];
            es += v.x*as.x + v.y*as.y + v.z*as.z + v.w*as.w;
            ed += v.x*ad.x + v.y*ad.y + v.z*ad.z + v.w*ad.w;
        }
        e_s2[t] = es; e_d2[t] = ed;
    }
    __syncthreads();
    if (t < NN) {
        const float edi = e_d2[t];
        float lv[NN]; float m = -1e30f;
        #pragma unroll
        for (int j = 0; j < NN; ++j) {
            float v = edi + e_s2[j]; v = v > 0.f ? v : SLOPE * v;
            lv[j] = v; m = fmaxf(m, v);
        }
        float s = 0.f;
        #pragma unroll
        for (int j = 0; j < NN; ++j) { lv[j] = __expf(lv[j] - m); s += lv[j]; }
        const float inv = 1.f / s;
        #pragma unroll
        for (int j = 0; j < NN; ++j) alpha2[t][j] = lv[j] * inv;
    }
    __syncthreads();
    {
        const int c = t & 63, i0 = (t >> 6) * 3;
        float v[NN];
        #pragma unroll
        for (int j = 0; j < NN; ++j) v[j] = u.s2.h2[j][c];
        const float bc = b2[c];
        #pragma unroll
        for (int ii = 0; ii < 3; ++ii) {
            const int i = i0 + ii;
            float acc = 0.f;
            #pragma unroll
            for (int j = 0; j < NN; ++j) acc = fmaf(alpha2[i][j], v[j], acc);
            u.s2.x3[i][c] = acc + bc > 0.f ? acc + bc : expm1f(acc + bc);
        }
    }
    __syncthreads();
    if (t < C2) {
        float s = 0.f;
        #pragma unroll
        for (int i = 0; i < NN; ++i) s += u.s2.x3[i][t];
        gph[t] = s * (1.0f / NN);
    }
    __syncthreads();
    if (t < 32) {
        float acc = bc1[t];
        for (int c = 0; c < C2; ++c) acc = fmaf(gph[c], Wc1[c * 32 + t], acc);
        hdn[t] = fmaxf(acc, 0.f);
    }
    __syncthreads();
    if (t == 0) {
        float acc = bc2[0];
        #pragma unroll
        for (int k = 0; k < 32; ++k) acc = fmaf(hdn[k], Wc2[k], acc);
        out[b] = acc;
    }
}

extern "C" void kernel_launch(void* const* d_in, const int* in_sizes, int n_in,
                              void* d_out, int out_size, void* d_ws, size_t ws_size,
                              hipStream_t stream) {
    const float* x   = (const float*)d_in[0];
    const float* W1  = (const float*)d_in[1];
    const float* as1 = (const float*)d_in[2];
    const float* ad1 = (const float*)d_in[3];
    const float* b1  = (const float*)d_in[4];
    const float* W2  = (const float*)d_in[5];
    const float* as2 = (const float*)d_in[6];
    const float* ad2 = (const float*)d_in[7];
    const float* b2  = (const float*)d_in[8];
    const float* Wc1 = (const float*)d_in[9];
    const float* bc1 = (const float*)d_in[10];
    const float* Wc2 = (const float*)d_in[11];
    const float* bc2 = (const float*)d_in[12];
    float* out = (float*)d_out;

    const int B = in_sizes[0] / (NN * FIN);

    if (ws_size >= 110592 && (B % 4) == 0) {
        unsigned short* wsB1 = (unsigned short*)d_ws;
        unsigned short* wsB2 = wsB1 + 34816;
        prep_weights<<<216, 256, 0, stream>>>(W1, as1, ad1, W2, as2, ad2, wsB1, wsB2);
        gat_mfma7<<<B / 4, 512, 0, stream>>>(x, wsB1, wsB2, b1, b2, Wc1, bc1, Wc2, bc2, out);
    } else {
        gat_fused_f32<<<B, 256, 0, stream>>>(x, W1, as1, ad1, b1, W2, as2, ad2, b2,
                                             Wc1, bc1, Wc2, bc2, out);
    }
}

// Round 9
// 145.285 us; speedup vs baseline: 1.0749x; 1.0749x over previous
//
#include <hip/hip_runtime.h>
#include <math.h>

typedef __attribute__((ext_vector_type(8))) short bf16x8;
typedef __attribute__((ext_vector_type(4))) float f32x4;

namespace {
constexpr int NN  = 12;
constexpr int FIN = 128;
constexpr int D1  = 256;
constexpr int C2  = 64;
constexpr float SLOPE = 0.2f;

__device__ __forceinline__ unsigned short f2bf(float f) {
    unsigned u = __builtin_bit_cast(unsigned, f);
    u += 0x7FFFu + ((u >> 16) & 1u);     // RNE
    return (unsigned short)(u >> 16);
}
// Pack two f32 -> two bf16 (RTZ) in ONE v_perm_b32: result = hi16(lo) | hi16(hi)<<16.
__device__ __forceinline__ unsigned pktrunc(float lo, float hi) {
    return __builtin_amdgcn_perm(__builtin_bit_cast(unsigned, hi),
                                 __builtin_bit_cast(unsigned, lo), 0x07060302u);
}
// ELU via hardware v_exp_f32 (~1e-7 err, ~5x cheaper than libm expm1f).
__device__ __forceinline__ float elu1(float x) { return x > 0.f ? x : __expf(x) - 1.f; }
__device__ __forceinline__ float lrelu(float x) { return x > 0.f ? x : SLOPE * x; }
}

// ---------------------------------------------------------------------------
// Pack B-operands into bf16 MFMA fragment layout, e-tiles folded in (R3).
// Weights stay RNE (packed once, reused by all blocks).
// ---------------------------------------------------------------------------
__global__ void prep_weights(const float* __restrict__ W1, const float* __restrict__ as1,
                             const float* __restrict__ ad1,
                             const float* __restrict__ W2, const float* __restrict__ as2,
                             const float* __restrict__ ad2,
                             unsigned short* __restrict__ wsB1, unsigned short* __restrict__ wsB2) {
    int t = blockIdx.x * 256 + threadIdx.x;
    if (t < 34816) {
        int i = t & 7, l = (t >> 3) & 63, kn = t >> 9;    // kn 0..67
        int kt = kn / 17, nt = kn % 17;
        int k = kt * 32 + (l >> 4) * 8 + i;
        float v = 0.f;
        if (nt < 16) {
            v = W1[k * 256 + nt * 16 + (l & 15)];
        } else {
            int cc = l & 15;
            if (cc < 4)      for (int c = 0; c < 64; ++c) v += W1[k * 256 + cc * 64 + c] * as1[cc * 64 + c];
            else if (cc < 8) for (int c = 0; c < 64; ++c) v += W1[k * 256 + (cc - 4) * 64 + c] * ad1[(cc - 4) * 64 + c];
        }
        wsB1[t] = f2bf(v);
    } else if (t < 55296) {
        int t2 = t - 34816;
        int i = t2 & 7, l = (t2 >> 3) & 63, kn = t2 >> 9; // kn 0..39
        int kt = kn / 5, nt = kn % 5;
        int k = kt * 32 + (l >> 4) * 8 + i;
        float v = 0.f;
        if (nt < 4) {
            v = W2[k * 64 + nt * 16 + (l & 15)];
        } else {
            int cc = l & 15;
            if (cc == 0)      for (int c = 0; c < 64; ++c) v += W2[k * 64 + c] * as2[c];
            else if (cc == 1) for (int c = 0; c < 64; ++c) v += W2[k * 64 + c] * ad2[c];
        }
        wsB2[t2] = f2bf(v);
    }
}

// ---------------------------------------------------------------------------
// Main fused kernel: 4 graphs (48 rows), 512 threads (8 waves) per block.
// Transposed aggregations (R8-proven). Bulk f32->bf16 packing via single
// v_perm_b32 truncation (pktrunc); alpha keeps RNE to avoid softmax bias.
// ---------------------------------------------------------------------------
__global__ __launch_bounds__(512, 4) void gat_mfma8(
    const float* __restrict__ x_in,
    const unsigned short* __restrict__ wsB1,
    const unsigned short* __restrict__ wsB2,
    const float* __restrict__ b1, const float* __restrict__ b2,
    const float* __restrict__ Wc1, const float* __restrict__ bc1,
    const float* __restrict__ Wc2, const float* __restrict__ bc2,
    float* __restrict__ out)
{
    // R0: x bf16 [48][128] swz (12288)           | x3T f32 [64 o][50 i] rows 200B (12800)
    // R1: h1T bf16 [256 o][64 j] swz (32768)     | h2T [64 o][64 j] (8192) + alpha2 [48 i][64 j] @+8192 (6144)
    // R2: alpha1 bf16 [4 h][48 i][64 j] (24576)  | x2 bf16 [48 i][256 o] rows 512B swz (24576)
    __shared__ __align__(16) unsigned char R0[13056];
    __shared__ __align__(16) unsigned char R1[32768];
    __shared__ __align__(16) unsigned char R2[24576];
    __shared__ float eS1[48][4], eD1[48][4];
    __shared__ float eS2[48], eD2[48];
    __shared__ float gpool[4][64];

    const int b = blockIdx.x, t = threadIdx.x;
    const int w = t >> 6, l = t & 63, l15 = l & 15, lq = l >> 4;

    // ---- P0: stage x (f32 -> bf16 LDS swizzled, pktrunc) + zero-fill pads
    {
        const float4* xs = (const float4*)(x_in + (size_t)b * (4 * NN * FIN));
        #pragma unroll
        for (int it = 0; it < 3; ++it) {
            int q = t + 512 * it;                          // 1536 float4
            float4 v = xs[q];
            int e0 = q << 2, r = e0 >> 7, k = e0 & 127;
            int addr = ((r << 8) + (k << 1)) ^ ((r & 7) << 4);
            *(uint2*)(R0 + addr) = make_uint2(pktrunc(v.x, v.y), pktrunc(v.z, v.w));
        }
        #pragma unroll
        for (int it = 0; it < 3; ++it)                     // zero alpha1 (24576 B)
            *(uint4*)(R2 + ((it * 512 + t) << 4)) = make_uint4(0, 0, 0, 0);
        {                                                  // zero h1T rows j=48..63 (512 x 16B)
            int col = t >> 1, bs = 6 + (t & 1);
            int addr = ((col << 7) + (bs << 4)) ^ ((col & 7) << 4);
            *(uint4*)(R1 + addr) = make_uint4(0, 0, 0, 0);
        }
    }
    __syncthreads();

    // ---- P1: GEMM1 (x @ [W1 | va1]) -> h1T bf16 + eS1/eD1 direct
    //      wave pair (2h, 2h+1) splits head h's 4 n-tiles into 2+2
    {
        const uint4* pb = (const uint4*)wsB1;
        const int h = w >> 1, half = w & 1;
        bf16x8 Bf[2][4];
        #pragma unroll
        for (int ngl = 0; ngl < 2; ++ngl)
            #pragma unroll
            for (int kt = 0; kt < 4; ++kt)
                Bf[ngl][kt] = __builtin_bit_cast(bf16x8, pb[(kt * 17 + (h * 4 + half * 2 + ngl)) * 64 + l]);
        bf16x8 Bfe[4];
        if (w == 0) {
            #pragma unroll
            for (int kt = 0; kt < 4; ++kt)
                Bfe[kt] = __builtin_bit_cast(bf16x8, pb[(kt * 17 + 16) * 64 + l]);
        }
        #pragma unroll
        for (int m = 0; m < 3; ++m) {
            int r = m * 16 + l15, abase = (r << 8) + (lq << 4), swz = (r & 7) << 4;
            bf16x8 Af[4];
            #pragma unroll
            for (int kt = 0; kt < 4; ++kt)
                Af[kt] = *(const bf16x8*)(R0 + ((abase + (kt << 6)) ^ swz));
            f32x4 acc[2];
            #pragma unroll
            for (int ngl = 0; ngl < 2; ++ngl) acc[ngl] = (f32x4){0.f, 0.f, 0.f, 0.f};
            #pragma unroll
            for (int ngl = 0; ngl < 2; ++ngl)
                #pragma unroll
                for (int kt = 0; kt < 4; ++kt)
                    acc[ngl] = __builtin_amdgcn_mfma_f32_16x16x32_bf16(Af[kt], Bf[ngl][kt], acc[ngl], 0, 0, 0);
            int row0 = m * 16 + lq * 4;
            #pragma unroll
            for (int ngl = 0; ngl < 2; ++ngl) {            // packed b64 store (4 consecutive j-rows)
                int col = h * 64 + (half * 2 + ngl) * 16 + l15;
                int addr = ((col << 7) + (row0 << 1)) ^ ((col & 7) << 4);
                *(uint2*)(R1 + addr) = make_uint2(pktrunc(acc[ngl][0], acc[ngl][1]),
                                                  pktrunc(acc[ngl][2], acc[ngl][3]));
            }
            if (w == 0) {
                f32x4 acce = (f32x4){0.f, 0.f, 0.f, 0.f};
                #pragma unroll
                for (int kt = 0; kt < 4; ++kt)
                    acce = __builtin_amdgcn_mfma_f32_16x16x32_bf16(Af[kt], Bfe[kt], acce, 0, 0, 0);
                if (l15 < 8) {
                    #pragma unroll
                    for (int reg = 0; reg < 4; ++reg) {
                        int row = row0 + reg;
                        if (l15 < 4) eS1[row][l15] = acce[reg];
                        else         eD1[row][l15 - 4] = acce[reg];
                    }
                }
            }
        }
    }
    __syncthreads();

    // ---- P2: softmax1 -> alpha1[h][i][j] bf16 (RNE), packed uint2 writes
    if (t < 192) {
        int g = t / 48, rem = t % 48, i = rem >> 2, h = rem & 3;
        int rowi = g * 12 + i;
        float edi = eD1[rowi][h];
        float lv[12]; float mx = -1e30f;
        #pragma unroll
        for (int j = 0; j < 12; ++j) {
            float v = lrelu(edi + eS1[g * 12 + j][h]);
            lv[j] = v; mx = fmaxf(mx, v);
        }
        float s = 0.f;
        #pragma unroll
        for (int j = 0; j < 12; ++j) { lv[j] = __expf(lv[j] - mx); s += lv[j]; }
        float inv = 1.f / s;
        unsigned char* base = R2 + h * 6144;
        int rb = rowi << 7, swz = (rowi & 7) << 4, ob = g * 24;
        #pragma unroll
        for (int p = 0; p < 3; ++p) {
            unsigned q0 = (unsigned)f2bf(lv[4*p]   * inv) | ((unsigned)f2bf(lv[4*p+1] * inv) << 16);
            unsigned q1 = (unsigned)f2bf(lv[4*p+2] * inv) | ((unsigned)f2bf(lv[4*p+3] * inv) << 16);
            int addr = (rb + ob + p * 8) ^ swz;
            *(uint2*)(base + addr) = make_uint2(q0, q1);
        }
    }
    __syncthreads();

    // ---- P3: aggregation1 TRANSPOSED: x2T[o][i] = sum_j h1T[o][j] * alpha[i][j]
    {
        const int h = w >> 1, half = w & 1;
        bf16x8 Ba[3][2];
        const unsigned char* ab = R2 + h * 6144;
        #pragma unroll
        for (int nt = 0; nt < 3; ++nt)
            #pragma unroll
            for (int kt = 0; kt < 2; ++kt) {
                int i = nt * 16 + l15;
                Ba[nt][kt] = *(const bf16x8*)(ab + (((i << 7) + (kt << 6) + (lq << 4)) ^ ((i & 7) << 4)));
            }
        __syncthreads();                                   // all alpha read before x2 overwrites R2
        #pragma unroll
        for (int mtl = 0; mtl < 2; ++mtl) {
            int mt = half * 2 + mtl;
            int o = h * 64 + mt * 16 + l15;
            bf16x8 Ah[2];
            #pragma unroll
            for (int kt = 0; kt < 2; ++kt)
                Ah[kt] = *(const bf16x8*)(R1 + (((o << 7) + (kt << 6) + (lq << 4)) ^ ((o & 7) << 4)));
            int o0 = h * 64 + mt * 16 + (lq << 2);
            float4 b1v = *(const float4*)(b1 + o0);
            float bb[4] = {b1v.x, b1v.y, b1v.z, b1v.w};
            #pragma unroll
            for (int nt = 0; nt < 3; ++nt) {
                f32x4 acc = (f32x4){0.f, 0.f, 0.f, 0.f};
                #pragma unroll
                for (int kt = 0; kt < 2; ++kt)
                    acc = __builtin_amdgcn_mfma_f32_16x16x32_bf16(Ah[kt], Ba[nt][kt], acc, 0, 0, 0);
                float e0 = elu1(acc[0] + bb[0]), e1 = elu1(acc[1] + bb[1]);
                float e2 = elu1(acc[2] + bb[2]), e3 = elu1(acc[3] + bb[3]);
                int i = nt * 16 + l15;
                int addr = ((i << 9) + (o0 << 1)) ^ ((i & 7) << 4);
                *(uint2*)(R2 + addr) = make_uint2(pktrunc(e0, e1), pktrunc(e2, e3));
            }
        }
    }
    __syncthreads();

    // ---- P4: GEMM2 (x2 @ [W2 | va2]) -> h2T bf16 + eS2/eD2; zero pads
    //      x2 [i][256 o] rows 512B; 15 (tile,m) units over 8 waves
    {
        if (t < 128) {                                     // zero h2T rows j=48..63
            int col = t >> 1, bs = 6 + (t & 1);
            int addr = ((col << 7) + (bs << 4)) ^ ((col & 7) << 4);
            *(uint4*)(R1 + addr) = make_uint4(0, 0, 0, 0);
        }
        if (t < 192) {                                     // zero alpha2 (6144 B)
            *(uint4*)(R1 + 8192 + (t << 4)) = make_uint4(0, 0, 0, 0);
            *(uint4*)(R1 + 8192 + ((t + 192) << 4)) = make_uint4(0, 0, 0, 0);
        }
        const uint4* pb2 = (const uint4*)wsB2;
        #pragma unroll
        for (int ui = 0; ui < 2; ++ui) {
            int u = w * 2 + ui;
            if (u < 15) {
                int tile = u / 3, m = u % 3;
                bf16x8 Bg[8];
                #pragma unroll
                for (int kt = 0; kt < 8; ++kt)
                    Bg[kt] = __builtin_bit_cast(bf16x8, pb2[(kt * 5 + tile) * 64 + l]);
                int r = m * 16 + l15, swz = (r & 7) << 4;
                f32x4 acc = (f32x4){0.f, 0.f, 0.f, 0.f};
                #pragma unroll
                for (int kt = 0; kt < 8; ++kt) {
                    int addr = ((r << 9) + (kt << 6) + (lq << 4)) ^ swz;
                    bf16x8 Ax = *(const bf16x8*)(R2 + addr);
                    acc = __builtin_amdgcn_mfma_f32_16x16x32_bf16(Ax, Bg[kt], acc, 0, 0, 0);
                }
                int row0 = m * 16 + lq * 4;
                if (tile < 4) {
                    int col = tile * 16 + l15;
                    int addr = ((col << 7) + (row0 << 1)) ^ ((col & 7) << 4);
                    *(uint2*)(R1 + addr) = make_uint2(pktrunc(acc[0], acc[1]),
                                                      pktrunc(acc[2], acc[3]));
                } else if (l15 < 2) {                      // e-tile
                    #pragma unroll
                    for (int reg = 0; reg < 4; ++reg) {
                        int row = row0 + reg;
                        if (l15 == 0) eS2[row] = acc[reg];
                        else          eD2[row] = acc[reg];
                    }
                }
            }
        }
    }
    __syncthreads();

    // ---- P5: softmax2 -> alpha2[i][j] bf16 (RNE), packed uint2 writes
    if (t < 48) {
        int g = t / 12;
        float edi = eD2[t];
        float lv[12]; float mx = -1e30f;
        #pragma unroll
        for (int j = 0; j < 12; ++j) {
            float v = lrelu(edi + eS2[g * 12 + j]);
            lv[j] = v; mx = fmaxf(mx, v);
        }
        float s = 0.f;
        #pragma unroll
        for (int j = 0; j < 12; ++j) { lv[j] = __expf(lv[j] - mx); s += lv[j]; }
        float inv = 1.f / s;
        int rb = t << 7, swz = (t & 7) << 4, ob = g * 24;
        #pragma unroll
        for (int p = 0; p < 3; ++p) {
            unsigned q0 = (unsigned)f2bf(lv[4*p]   * inv) | ((unsigned)f2bf(lv[4*p+1] * inv) << 16);
            unsigned q1 = (unsigned)f2bf(lv[4*p+2] * inv) | ((unsigned)f2bf(lv[4*p+3] * inv) << 16);
            int addr = 8192 + ((rb + ob + p * 8) ^ swz);
            *(uint2*)(R1 + addr) = make_uint2(q0, q1);
        }
    }
    __syncthreads();

    // ---- P6: aggregation2 TRANSPOSED: x3T[o][i] -> R0 rows 200 B
    //      12 (mt, nt) units: waves 0..3 -> mt=w, nt {0,1}; waves 4..7 -> mt=w-4, nt=2
    {
        const int mt = w & 3;
        const int nt0 = (w < 4) ? 0 : 2;
        const int ntc = (w < 4) ? 2 : 1;
        int o = mt * 16 + l15;
        bf16x8 Ah2[2];
        #pragma unroll
        for (int kt = 0; kt < 2; ++kt)
            Ah2[kt] = *(const bf16x8*)(R1 + (((o << 7) + (kt << 6) + (lq << 4)) ^ ((o & 7) << 4)));
        int ost = mt * 16 + (lq << 2);
        float4 b2v = *(const float4*)(b2 + ost);
        float bb[4] = {b2v.x, b2v.y, b2v.z, b2v.w};
        for (int ni = 0; ni < ntc; ++ni) {
            int nt = nt0 + ni;
            int i = nt * 16 + l15;
            bf16x8 Ba2[2];
            #pragma unroll
            for (int kt = 0; kt < 2; ++kt)
                Ba2[kt] = *(const bf16x8*)(R1 + 8192 + (((i << 7) + (kt << 6) + (lq << 4)) ^ ((i & 7) << 4)));
            f32x4 acc = (f32x4){0.f, 0.f, 0.f, 0.f};
            #pragma unroll
            for (int kt = 0; kt < 2; ++kt)
                acc = __builtin_amdgcn_mfma_f32_16x16x32_bf16(Ah2[kt], Ba2[kt], acc, 0, 0, 0);
            #pragma unroll
            for (int reg = 0; reg < 4; ++reg)
                *(float*)(R0 + (ost + reg) * 200 + (i << 2)) = elu1(acc[reg] + bb[reg]);
        }
    }
    __syncthreads();

    // ---- pool: g[o] = mean over the graph's 12 nodes (contiguous in x3T row)
    if (t < 256) {
        int o = t & 63, g = t >> 6;
        const unsigned char* row = R0 + o * 200 + g * 48;
        float s = 0.f;
        #pragma unroll
        for (int p = 0; p < 6; ++p) {
            float2 v = *(const float2*)(row + p * 8);
            s += v.x + v.y;
        }
        gpool[g][o] = s * (1.0f / 12.0f);
    }
    __syncthreads();

    // ---- classifier 64 -> 32 (relu) -> 1
    if (t < 128) {
        int g = t >> 5, nr = t & 31;
        float acc = bc1[nr];
        #pragma unroll
        for (int cc = 0; cc < 64; ++cc)
            acc = fmaf(gpool[g][cc], Wc1[cc * 32 + nr], acc);
        float val = fmaxf(acc, 0.f) * Wc2[nr];
        #pragma unroll
        for (int msk = 1; msk < 32; msk <<= 1) val += __shfl_xor(val, msk);
        if (nr == 0) out[b * 4 + g] = val + bc2[0];
    }
}

// ---------------------------------------------------------------------------
// f32 fallback — used only if ws too small or B % 4 != 0
// ---------------------------------------------------------------------------
__global__ __launch_bounds__(256, 4) void gat_fused_f32(
    const float* __restrict__ x_in, const float* __restrict__ W1,
    const float* __restrict__ a_src1, const float* __restrict__ a_dst1,
    const float* __restrict__ b1, const float* __restrict__ W2,
    const float* __restrict__ a_src2, const float* __restrict__ a_dst2,
    const float* __restrict__ b2, const float* __restrict__ Wc1,
    const float* __restrict__ bc1, const float* __restrict__ Wc2,
    const float* __restrict__ bc2, float* __restrict__ out)
{
    __shared__ union {
        float x_l[NN][FIN];
        struct { float h2[NN][C2]; float x3[NN][C2]; } s2;
    } u;
    __shared__ float h1s[NN][D1];
    __shared__ float x2s[NN][D1];
    __shared__ float alpha1[NN][NN][4];
    __shared__ float e_s1[NN][4], e_d1[NN][4];
    __shared__ float e_s2[NN], e_d2[NN];
    __shared__ float alpha2[NN][NN];
    __shared__ float gph[C2];
    __shared__ float hdn[32];

    const int b = blockIdx.x, t = threadIdx.x;
    const float* xb = x_in + (size_t)b * (NN * FIN);
    for (int i = t; i < NN * FIN; i += 256) (&u.x_l[0][0])[i] = xb[i];
    __syncthreads();
    {
        const int o0 = (t & 127) * 2, n0 = (t >> 7) * 6;
        float acc[6][2];
        #pragma unroll
        for (int i = 0; i < 6; ++i) { acc[i][0] = 0.f; acc[i][1] = 0.f; }
        for (int f = 0; f < FIN; f += 4) {
            float4 xv[6];
            #pragma unroll
            for (int i = 0; i < 6; ++i) xv[i] = *(const float4*)&u.x_l[n0 + i][f];
            #pragma unroll
            for (int k = 0; k < 4; ++k) {
                const float2 wv = *(const float2*)&W1[(f + k) * D1 + o0];
                #pragma unroll
                for (int i = 0; i < 6; ++i) {
                    const float xs = ((const float*)&xv[i])[k];
                    acc[i][0] = fmaf(xs, wv.x, acc[i][0]);
                    acc[i][1] = fmaf(xs, wv.y, acc[i][1]);
                }
            }
        }
        #pragma unroll
        for (int i = 0; i < 6; ++i) { h1s[n0+i][o0] = acc[i][0]; h1s[n0+i][o0+1] = acc[i][1]; }
    }
    __syncthreads();
    if (t < NN * 4) {
        const int n = t >> 2, h = t & 3;
        float es = 0.f, ed = 0.f;
        for (int c = 0; c < 64; ++c) {
            const float v = h1s[n][h * 64 + c];
            es = fmaf(v, a_src1[h * 64 + c], es);
            ed = fmaf(v, a_dst1[h * 64 + c], ed);
        }
        e_s1[n][h] = es; e_d1[n][h] = ed;
    }
    __syncthreads();
    if (t < NN * 4) {
        const int i = t >> 2, h = t & 3;
        const float edi = e_d1[i][h];
        float lv[NN]; float m = -1e30f;
        #pragma unroll
        for (int j = 0; j < NN; ++j) {
            float v = edi + e_s1[j][h]; v = v > 0.f ? v : SLOPE * v;
            lv[j] = v; m = fmaxf(m, v);
        }
        float s = 0.f;
        #pragma unroll
        for (int j = 0; j < NN; ++j) { lv[j] = __expf(lv[j] - m); s += lv[j]; }
        const float inv = 1.f / s;
        #pragma unroll
        for (int j = 0; j < NN; ++j) alpha1[i][j][h] = lv[j] * inv;
    }
    __syncthreads();
    {
        const int o = t, h = o >> 6;
        const float bo = b1[o];
        float v[NN];
        #pragma unroll
        for (int j = 0; j < NN; ++j) v[j] = h1s[j][o];
        #pragma unroll
        for (int i = 0; i < NN; ++i) {
            float acc = 0.f;
            #pragma unroll
            for (int j = 0; j < NN; ++j) acc = fmaf(alpha1[i][j][h], v[j], acc);
            x2s[i][o] = acc + bo > 0.f ? acc + bo : expm1f(acc + bo);
        }
    }
    __syncthreads();
    {
        const int c = t & 63, n0 = (t >> 6) * 3;
        float acc[3] = {0.f, 0.f, 0.f};
        for (int f = 0; f < D1; f += 4) {
            float4 xv[3];
            #pragma unroll
            for (int i = 0; i < 3; ++i) xv[i] = *(const float4*)&x2s[n0 + i][f];
            #pragma unroll
            for (int k = 0; k < 4; ++k) {
                const float wv = W2[(f + k) * C2 + c];
                #pragma unroll
                for (int i = 0; i < 3; ++i) acc[i] = fmaf(((const float*)&xv[i])[k], wv, acc[i]);
            }
        }
        #pragma unroll
        for (int i = 0; i < 3; ++i) u.s2.h2[n0 + i][c] = acc[i];
    }
    __syncthreads();
    if (t < NN) {
        float es = 0.f, ed = 0.f;
        for (int c = 0; c < 64; c += 4) {
            const float4 v  = *(const float4*)&u.s2.h2[t][c];
            const float4 as = *(const float4*)&a_src2[c];
            const float4 ad = *(const float4*)&a_dst2[c];
            es += v.x*as.x + v.y*as.y + v.z*as.z + v.w*as.w;
            ed += v.x*ad.x + v.y*ad.y + v.z*ad.z + v.w*ad.w;
        }
        e_s2[t] = es; e_d2[t] = ed;
    }
    __syncthreads();
    if (t < NN) {
        const float edi = e_d2[t];
        float lv[NN]; float m = -1e30f;
        #pragma unroll
        for (int j = 0; j < NN; ++j) {
            float v = edi + e_s2[j]; v = v > 0.f ? v : SLOPE * v;
            lv[j] = v; m = fmaxf(m, v);
        }
        float s = 0.f;
        #pragma unroll
        for (int j = 0; j < NN; ++j) { lv[j] = __expf(lv[j] - m); s += lv[j]; }
        const float inv = 1.f / s;
        #pragma unroll
        for (int j = 0; j < NN; ++j) alpha2[t][j] = lv[j] * inv;
    }
    __syncthreads();
    {
        const int c = t & 63, i0 = (t >> 6) * 3;
        float v[NN];
        #pragma unroll
        for (int j = 0; j < NN; ++j) v[j] = u.s2.h2[j][c];
        const float bc = b2[c];
        #pragma unroll
        for (int ii = 0; ii < 3; ++ii) {
            const int i = i0 + ii;
            float acc = 0.f;
            #pragma unroll
            for (int j = 0; j < NN; ++j) acc = fmaf(alpha2[i][j], v[j], acc);
            u.s2.x3[i][c] = acc + bc > 0.f ? acc + bc : expm1f(acc + bc);
        }
    }
    __syncthreads();
    if (t < C2) {
        float s = 0.f;
        #pragma unroll
        for (int i = 0; i < NN; ++i) s += u.s2.x3[i][t];
        gph[t] = s * (1.0f / NN);
    }
    __syncthreads();
    if (t < 32) {
        float acc = bc1[t];
        for (int c = 0; c < C2; ++c) acc = fmaf(gph[c], Wc1[c * 32 + t], acc);
        hdn[t] = fmaxf(acc, 0.f);
    }
    __syncthreads();
    if (t == 0) {
        float acc = bc2[0];
        #pragma unroll
        for (int k = 0; k < 32; ++k) acc = fmaf(hdn[k], Wc2[k], acc);
        out[b] = acc;
    }
}

extern "C" void kernel_launch(void* const* d_in, const int* in_sizes, int n_in,
                              void* d_out, int out_size, void* d_ws, size_t ws_size,
                              hipStream_t stream) {
    const float* x   = (const float*)d_in[0];
    const float* W1  = (const float*)d_in[1];
    const float* as1 = (const float*)d_in[2];
    const float* ad1 = (const float*)d_in[3];
    const float* b1  = (const float*)d_in[4];
    const float* W2  = (const float*)d_in[5];
    const float* as2 = (const float*)d_in[6];
    const float* ad2 = (const float*)d_in[7];
    const float* b2  = (const float*)d_in[8];
    const float* Wc1 = (const float*)d_in[9];
    const float* bc1 = (const float*)d_in[10];
    const float* Wc2 = (const float*)d_in[11];
    const float* bc2 = (const float*)d_in[12];
    float* out = (float*)d_out;

    const int B = in_sizes[0] / (NN * FIN);

    if (ws_size >= 110592 && (B % 4) == 0) {
        unsigned short* wsB1 = (unsigned short*)d_ws;
        unsigned short* wsB2 = wsB1 + 34816;
        prep_weights<<<216, 256, 0, stream>>>(W1, as1, ad1, W2, as2, ad2, wsB1, wsB2);
        gat_mfma8<<<B / 4, 512, 0, stream>>>(x, wsB1, wsB2, b1, b2, Wc1, bc1, Wc2, bc2, out);
    } else {
        gat_fused_f32<<<B, 256, 0, stream>>>(x, W1, as1, ad1, b1, W2, as2, ad2, b2,
                                             Wc1, bc1, Wc2, bc2, out);
    }
}